// Round 4
// baseline (320.026 us; speedup 1.0000x reference)
//
#include <hip/hip_runtime.h>
#include <math.h>

// Problem constants (fixed by the reference)
#define B_  8
#define C_  256
#define N_  4096        // H*W
#define CQK 32          // C/8
#define NJC (N_ / 128)  // 32 j-iterations of 128
#define PLD 136         // p_s row stride in shorts (128 + 8 pad)

using frag  = __attribute__((ext_vector_type(8))) short;   // 8 bf16 = 16 B
using f32x4 = __attribute__((ext_vector_type(4))) float;

__device__ __forceinline__ unsigned short f2bf(float f) {   // RNE fp32 -> bf16
    unsigned u = __float_as_uint(f);
    u += 0x7fffu + ((u >> 16) & 1u);
    return (unsigned short)(u >> 16);
}
__device__ __forceinline__ float bf2f(unsigned short h) {
    return __uint_as_float(((unsigned)h) << 16);
}
#define PK2(a, b) (((unsigned)(a)) | (((unsigned)(b)) << 16))

__device__ __forceinline__ f32x4 fmax4(f32x4 a, f32x4 b) {
    f32x4 r;
    r[0] = fmaxf(a[0], b[0]); r[1] = fmaxf(a[1], b[1]);
    r[2] = fmaxf(a[2], b[2]); r[3] = fmaxf(a[3], b[3]);
    return r;
}

// ---------------------------------------------------------------------------
// Kernel 0: weight prep -> frag-ordered bf16 weights in ws.
//   whf: 20 groups x 8 kc x 64 lanes x 8 bf16  (g 0,1=q; 2,3=k; 4..19=v)
//   wlf: 4 groups (q,k lo part), same shape.
// A-frag: lane(l16,quad) holds W[g*16 + l16][kc*32 + quad*8 + 0..7]
// grid 40 x 256.
// ---------------------------------------------------------------------------
__global__ __launch_bounds__(256) void wprep_kernel(
    const float* __restrict__ wq, const float* __restrict__ wk,
    const float* __restrict__ wv,
    unsigned short* __restrict__ whf, unsigned short* __restrict__ wlf)
{
    const int fid  = blockIdx.x * 256 + threadIdx.x;   // 0..10239
    if (fid >= 20 * 8 * 64) return;
    const int g    = fid >> 9;
    const int kc   = (fid >> 6) & 7;
    const int lane = fid & 63;
    const int r16  = lane & 15, q = lane >> 4;

    const float* src; int row;
    if (g < 2)      { src = wq; row = g * 16 + r16; }
    else if (g < 4) { src = wk; row = (g - 2) * 16 + r16; }
    else            { src = wv; row = (g - 4) * 16 + r16; }

    const float* wp = src + row * 256 + kc * 32 + q * 8;
    float v[8];
#pragma unroll
    for (int j = 0; j < 8; ++j) v[j] = wp[j];

    unsigned short h[8];
#pragma unroll
    for (int j = 0; j < 8; ++j) h[j] = f2bf(v[j]);
    uint4 U;
    U.x = PK2(h[0], h[1]); U.y = PK2(h[2], h[3]);
    U.z = PK2(h[4], h[5]); U.w = PK2(h[6], h[7]);
    *(uint4*)&whf[(size_t)fid * 8] = U;

    if (g < 4) {
        unsigned short l[8];
#pragma unroll
        for (int j = 0; j < 8; ++j) l[j] = f2bf(v[j] - bf2f(h[j]));
        uint4 V;
        V.x = PK2(l[0], l[1]); V.y = PK2(l[2], l[3]);
        V.z = PK2(l[4], l[5]); V.w = PK2(l[6], l[7]);
        *(uint4*)&wlf[(size_t)fid * 8] = V;
    }
}

// ---------------------------------------------------------------------------
// Kernel 1: MFMA qkv projection — x read ONCE.
// grid (N/64, B), 256 threads (4 waves). Wave w owns pixels n0 + w*16 + l16,
// computes ALL 320 out-channels (20 m-tiles). W frags streamed from global
// (bf16, frag-ordered, L1/L2-resident). X gathered fp32 -> bf16 hi/lo.
// Outputs: qh/ql, kh/kl [B][N][32] bf16 hi/lo; vbf [B][C][N] bf16.
// ---------------------------------------------------------------------------
__global__ __launch_bounds__(256, 2) void proj_kernel(
    const float* __restrict__ x,
    const float* __restrict__ bq, const float* __restrict__ bk,
    const float* __restrict__ bv,
    const unsigned short* __restrict__ whf, const unsigned short* __restrict__ wlf,
    unsigned short* __restrict__ qh, unsigned short* __restrict__ ql,
    unsigned short* __restrict__ kh, unsigned short* __restrict__ kl,
    unsigned short* __restrict__ vbf)
{
    const int tid  = threadIdx.x;
    const int w    = tid >> 6;
    const int lane = tid & 63;
    const int quad = lane >> 4;
    const int l16  = lane & 15;
    const int n0   = blockIdx.x * 64;
    const int b    = blockIdx.y;
    const int n    = n0 + w * 16 + l16;

    const frag* wh = (const frag*)whf;
    const frag* wl = (const frag*)wlf;

    f32x4 a[20];
#pragma unroll
    for (int g = 0; g < 20; ++g) a[g] = (f32x4){0.f, 0.f, 0.f, 0.f};

    for (int kc = 0; kc < 8; ++kc) {
        const float* xp = x + (size_t)b * C_ * N_ + (size_t)(kc * 32 + quad * 8) * N_ + n;
        float xv[8];
#pragma unroll
        for (int j = 0; j < 8; ++j) xv[j] = xp[(size_t)j * N_];

        frag bh, bl;
#pragma unroll
        for (int j = 0; j < 8; ++j) {
            const unsigned short hb = f2bf(xv[j]);
            bh[j] = (short)hb;
            bl[j] = (short)f2bf(xv[j] - bf2f(hb));
        }

#pragma unroll
        for (int g = 0; g < 4; ++g) {
            const frag ah = wh[(g * 8 + kc) * 64 + lane];
            const frag al = wl[(g * 8 + kc) * 64 + lane];
            a[g] = __builtin_amdgcn_mfma_f32_16x16x32_bf16(ah, bh, a[g], 0, 0, 0);
            a[g] = __builtin_amdgcn_mfma_f32_16x16x32_bf16(al, bh, a[g], 0, 0, 0);
            a[g] = __builtin_amdgcn_mfma_f32_16x16x32_bf16(ah, bl, a[g], 0, 0, 0);
        }
#pragma unroll
        for (int g = 4; g < 20; ++g) {
            const frag ah = wh[(g * 8 + kc) * 64 + lane];
            a[g] = __builtin_amdgcn_mfma_f32_16x16x32_bf16(ah, bh, a[g], 0, 0, 0);
        }
    }

    // ---- epilogue.  D[m = quad*4+r (within tile)][col = l16 = pixel] ----
#pragma unroll
    for (int g = 0; g < 4; ++g) {
        const bool isq = (g < 2);
        const float* bias = isq ? bq : bk;
        const int dbase = (isq ? g : g - 2) * 16 + quad * 4;
        unsigned short hs[4], ls[4];
#pragma unroll
        for (int r = 0; r < 4; ++r) {
            const float f = a[g][r] + bias[dbase + r];
            hs[r] = f2bf(f);
            ls[r] = f2bf(f - bf2f(hs[r]));
        }
        const size_t off = ((size_t)(b * N_ + n)) * 32 + dbase;
        *(uint2*)&(isq ? qh : kh)[off] = make_uint2(PK2(hs[0], hs[1]), PK2(hs[2], hs[3]));
        *(uint2*)&(isq ? ql : kl)[off] = make_uint2(PK2(ls[0], ls[1]), PK2(ls[2], ls[3]));
    }
#pragma unroll
    for (int g = 4; g < 20; ++g) {
#pragma unroll
        for (int r = 0; r < 4; ++r) {
            const int c = (g - 4) * 16 + quad * 4 + r;
            vbf[((size_t)b * C_ + c) * N_ + n] = f2bf(a[g][r] + bv[c]);
        }
    }
}

// ---------------------------------------------------------------------------
// Kernel 2: MFMA flash attention, J=128 chunks, single barrier/iter,
// double-buffered P in LDS, K frags direct from global, V prefetched.
// grid (N/64, B), 256 threads (4 waves).
// ---------------------------------------------------------------------------
__global__ __launch_bounds__(256, 2) void attn_kernel(
    const unsigned short* __restrict__ qh, const unsigned short* __restrict__ ql,
    const unsigned short* __restrict__ khg, const unsigned short* __restrict__ klg,
    const unsigned short* __restrict__ vbf,
    const float* __restrict__ x, const float* __restrict__ alpha_p,
    float* __restrict__ out)
{
    __shared__ __align__(16) short p_s[2][64 * PLD];   // 34.8 KB
    __shared__ float alpha_s[2][64];
    __shared__ float l_s[64];

    const int tid  = threadIdx.x;
    const int w    = tid >> 6;
    const int lane = tid & 63;
    const int quad = lane >> 4;
    const int l16  = lane & 15;
    const int b    = blockIdx.y;
    const int i0   = blockIdx.x * 64;

    // Q B-frags (constant): lane holds q[i = i0+16w+l16][d = 8*quad..+8]
    const size_t qoff = ((size_t)(b * N_ + i0 + w * 16 + l16)) * 32 + quad * 8;
    const frag qhf = *(const frag*)(qh + qoff);
    const frag qlf = *(const frag*)(ql + qoff);

    const unsigned short* khb = khg + (size_t)b * N_ * 32;
    const unsigned short* klb = klg + (size_t)b * N_ * 32;
    const unsigned short* vb  = vbf + (size_t)b * C_ * N_;

    f32x4 o[4][4];   // [i-subtile][c-subtile], c = 64w + 16*ct + l16
#pragma unroll
    for (int it = 0; it < 4; ++it)
#pragma unroll
        for (int ct = 0; ct < 4; ++ct) o[it][ct] = (f32x4){0.f, 0.f, 0.f, 0.f};

    float m_run = -INFINITY, l_run = 0.f;

    for (int jc = 0; jc < NJC; ++jc) {
        const int buf = jc & 1;

        // ---- prefetch V frags for this chunk (consumed after the barrier;
        //      latency hides behind S + softmax; can't sink past barrier) ----
        frag vf[4][4];
#pragma unroll
        for (int ks = 0; ks < 4; ++ks)
#pragma unroll
            for (int ct = 0; ct < 4; ++ct)
                vf[ks][ct] = *(const frag*)(vb
                    + (size_t)(w * 64 + ct * 16 + l16) * N_
                    + jc * 128 + ks * 32 + quad * 8);

        // ---- S^T: K frags straight from global (1KB contiguous per load,
        //      shared by all 4 waves -> L1). 3-MFMA split-bf16. ----
        f32x4 st[8];
#pragma unroll
        for (int js = 0; js < 8; ++js) {
            const size_t koff = ((size_t)(jc * 128 + js * 16 + l16)) * 32 + quad * 8;
            const frag ka = *(const frag*)(khb + koff);
            const frag kb = *(const frag*)(klb + koff);
            f32x4 s = (f32x4){0.f, 0.f, 0.f, 0.f};
            s = __builtin_amdgcn_mfma_f32_16x16x32_bf16(ka, qhf, s, 0, 0, 0);
            s = __builtin_amdgcn_mfma_f32_16x16x32_bf16(ka, qlf, s, 0, 0, 0);
            s = __builtin_amdgcn_mfma_f32_16x16x32_bf16(kb, qhf, s, 0, 0, 0);
            st[js] = s;
        }

        // ---- online softmax, rows i = w*16 + l16 (tree reductions) ----
        f32x4 t0 = fmax4(fmax4(st[0], st[1]), fmax4(st[2], st[3]));
        f32x4 t1 = fmax4(fmax4(st[4], st[5]), fmax4(st[6], st[7]));
        t0 = fmax4(t0, t1);
        float mx = fmaxf(fmaxf(t0[0], t0[1]), fmaxf(t0[2], t0[3]));
        mx = fmaxf(mx, __shfl_xor(mx, 16));
        mx = fmaxf(mx, __shfl_xor(mx, 32));
        const float mnew = fmaxf(m_run, mx);
        const float sc   = __expf(m_run - mnew);

        f32x4 ps4 = (f32x4){0.f, 0.f, 0.f, 0.f};
#pragma unroll
        for (int js = 0; js < 8; ++js) {
#pragma unroll
            for (int r = 0; r < 4; ++r) st[js][r] = __expf(st[js][r] - mnew);
            ps4[0] += st[js][0]; ps4[1] += st[js][1];
            ps4[2] += st[js][2]; ps4[3] += st[js][3];
        }
        float ps = (ps4[0] + ps4[1]) + (ps4[2] + ps4[3]);
        ps += __shfl_xor(ps, 16);
        ps += __shfl_xor(ps, 32);
        l_run = l_run * sc + ps;
        m_run = mnew;
        if (quad == 0) alpha_s[buf][w * 16 + l16] = sc;

        // ---- P -> bf16 (round-half-up + v_perm pack) -> LDS ----
#pragma unroll
        for (int js = 0; js < 8; ++js) {
            const unsigned a0 = __float_as_uint(st[js][0]) + 0x8000u;
            const unsigned a1 = __float_as_uint(st[js][1]) + 0x8000u;
            const unsigned a2 = __float_as_uint(st[js][2]) + 0x8000u;
            const unsigned a3 = __float_as_uint(st[js][3]) + 0x8000u;
            const unsigned p01 = __builtin_amdgcn_perm(a1, a0, 0x07060302u);
            const unsigned p23 = __builtin_amdgcn_perm(a3, a2, 0x07060302u);
            *(uint2*)&p_s[buf][(w * 16 + l16) * PLD + js * 16 + quad * 4] =
                make_uint2(p01, p23);
        }
        __syncthreads();   // single barrier: p_s[buf]+alpha ready; buf reuse safe

        // ---- rescale O ----
#pragma unroll
        for (int it = 0; it < 4; ++it)
#pragma unroll
            for (int r = 0; r < 4; ++r) {
                const float al = alpha_s[buf][it * 16 + quad * 4 + r];
#pragma unroll
                for (int ct = 0; ct < 4; ++ct) o[it][ct][r] *= al;
            }

        // ---- PV: A = P (LDS), B = V (prefetched regs) ----
#pragma unroll
        for (int ks = 0; ks < 4; ++ks) {
#pragma unroll
            for (int it = 0; it < 4; ++it) {
                const frag pf = *(const frag*)&p_s[buf][(it * 16 + l16) * PLD
                                                       + ks * 32 + quad * 8];
#pragma unroll
                for (int ct = 0; ct < 4; ++ct)
                    o[it][ct] = __builtin_amdgcn_mfma_f32_16x16x32_bf16(
                        pf, vf[ks][ct], o[it][ct], 0, 0, 0);
            }
        }
    }

    // ---- epilogue: out = alpha * O / l + x ----
    if (quad == 0) l_s[w * 16 + l16] = l_run;
    __syncthreads();
    const float av = alpha_p[0];

#pragma unroll
    for (int it = 0; it < 4; ++it) {
        float invl[4];
#pragma unroll
        for (int r = 0; r < 4; ++r) invl[r] = 1.f / l_s[it * 16 + quad * 4 + r];
#pragma unroll
        for (int ct = 0; ct < 4; ++ct) {
            const int c = w * 64 + ct * 16 + l16;
            const size_t base = (size_t)b * C_ * N_ + (size_t)c * N_
                                + i0 + it * 16 + quad * 4;
            const float4 xv = *(const float4*)(x + base);
            float4 ov;
            ov.x = av * (o[it][ct][0] * invl[0]) + xv.x;
            ov.y = av * (o[it][ct][1] * invl[1]) + xv.y;
            ov.z = av * (o[it][ct][2] * invl[2]) + xv.z;
            ov.w = av * (o[it][ct][3] * invl[3]) + xv.w;
            *(float4*)(out + base) = ov;
        }
    }
}

// ---------------------------------------------------------------------------
extern "C" void kernel_launch(void* const* d_in, const int* in_sizes, int n_in,
                              void* d_out, int out_size, void* d_ws, size_t ws_size,
                              hipStream_t stream)
{
    const float* x  = (const float*)d_in[0];
    const float* wq = (const float*)d_in[1];
    const float* bq = (const float*)d_in[2];
    const float* wk = (const float*)d_in[3];
    const float* bk = (const float*)d_in[4];
    const float* wv = (const float*)d_in[5];
    const float* bv = (const float*)d_in[6];
    const float* al = (const float*)d_in[7];
    float* out = (float*)d_out;

    // workspace: qh,ql,kh,kl 2MB each; vbf 16MB; whf 160KB; wlf 32KB
    char* ws = (char*)d_ws;
    unsigned short* qh  = (unsigned short*)(ws + 0);
    unsigned short* ql  = (unsigned short*)(ws + (size_t)2  * 1024 * 1024);
    unsigned short* kh  = (unsigned short*)(ws + (size_t)4  * 1024 * 1024);
    unsigned short* kl  = (unsigned short*)(ws + (size_t)6  * 1024 * 1024);
    unsigned short* vbf = (unsigned short*)(ws + (size_t)8  * 1024 * 1024);
    unsigned short* whf = (unsigned short*)(ws + (size_t)24 * 1024 * 1024);
    unsigned short* wlf = (unsigned short*)(ws + (size_t)24 * 1024 * 1024 + 256 * 1024);

    wprep_kernel<<<40, 256, 0, stream>>>(wq, wk, wv, whf, wlf);
    proj_kernel<<<dim3(N_ / 64, B_), 256, 0, stream>>>(
        x, bq, bk, bv, whf, wlf, qh, ql, kh, kl, vbf);
    attn_kernel<<<dim3(N_ / 64, B_), 256, 0, stream>>>(
        qh, ql, kh, kl, vbf, x, al, out);
}

// Round 5
// 295.627 us; speedup vs baseline: 1.0825x; 1.0825x over previous
//
#include <hip/hip_runtime.h>
#include <math.h>

// Problem constants (fixed by the reference)
#define B_  8
#define C_  256
#define N_  4096        // H*W
#define NJC (N_ / 128)  // 32 j-iterations of 128
#define PLD 136         // p_s row stride in shorts (128 + 8 pad)

using frag  = __attribute__((ext_vector_type(8))) short;   // 8 bf16 = 16 B
using f32x4 = __attribute__((ext_vector_type(4))) float;

__device__ __forceinline__ unsigned short f2bf(float f) {   // RNE fp32 -> bf16
    unsigned u = __float_as_uint(f);
    u += 0x7fffu + ((u >> 16) & 1u);
    return (unsigned short)(u >> 16);
}
__device__ __forceinline__ float bf2f(unsigned short h) {
    return __uint_as_float(((unsigned)h) << 16);
}
#define PK2(a, b) (((unsigned)(a)) | (((unsigned)(b)) << 16))

__device__ __forceinline__ f32x4 fmax4(f32x4 a, f32x4 b) {
    f32x4 r;
    r[0] = fmaxf(a[0], b[0]); r[1] = fmaxf(a[1], b[1]);
    r[2] = fmaxf(a[2], b[2]); r[3] = fmaxf(a[3], b[3]);
    return r;
}

// ---------------------------------------------------------------------------
// Kernel 0: weight prep -> frag-ordered bf16 weights in ws.
//   whf: 20 groups x 8 kc x 64 lanes x 8 bf16  (g 0,1=q; 2,3=k; 4..19=v)
//   wlf: 4 groups (q,k lo part), same shape.
// A-frag: lane(l16,quad) holds W[g*16 + l16][kc*32 + quad*8 + 0..7]
// ---------------------------------------------------------------------------
__global__ __launch_bounds__(256) void wprep_kernel(
    const float* __restrict__ wq, const float* __restrict__ wk,
    const float* __restrict__ wv,
    unsigned short* __restrict__ whf, unsigned short* __restrict__ wlf)
{
    const int fid  = blockIdx.x * 256 + threadIdx.x;   // 0..10239
    if (fid >= 20 * 8 * 64) return;
    const int g    = fid >> 9;
    const int kc   = (fid >> 6) & 7;
    const int lane = fid & 63;
    const int r16  = lane & 15, q = lane >> 4;

    const float* src; int row;
    if (g < 2)      { src = wq; row = g * 16 + r16; }
    else if (g < 4) { src = wk; row = (g - 2) * 16 + r16; }
    else            { src = wv; row = (g - 4) * 16 + r16; }

    const float* wp = src + row * 256 + kc * 32 + q * 8;
    float v[8];
#pragma unroll
    for (int j = 0; j < 8; ++j) v[j] = wp[j];

    unsigned short h[8];
#pragma unroll
    for (int j = 0; j < 8; ++j) h[j] = f2bf(v[j]);
    uint4 U;
    U.x = PK2(h[0], h[1]); U.y = PK2(h[2], h[3]);
    U.z = PK2(h[4], h[5]); U.w = PK2(h[6], h[7]);
    *(uint4*)&whf[(size_t)fid * 8] = U;

    if (g < 4) {
        unsigned short l[8];
#pragma unroll
        for (int j = 0; j < 8; ++j) l[j] = f2bf(v[j] - bf2f(h[j]));
        uint4 V;
        V.x = PK2(l[0], l[1]); V.y = PK2(l[2], l[3]);
        V.z = PK2(l[4], l[5]); V.w = PK2(l[6], l[7]);
        *(uint4*)&wlf[(size_t)fid * 8] = V;
    }
}

// ---------------------------------------------------------------------------
// Kernel 1: MFMA qkv projection — x staged ONCE into LDS (packed hi|lo).
// grid (N/64, B), 256 threads (4 waves). Wave w owns pixels n0 + w*16 + l16,
// computes ALL 320 out-channels. W frags streamed from global (L2-resident);
// B-frags rebuilt from LDS with v_perm (no global x in the kc loop).
// ---------------------------------------------------------------------------
__global__ __launch_bounds__(256, 2) void proj_kernel(
    const float* __restrict__ x,
    const float* __restrict__ bq, const float* __restrict__ bk,
    const float* __restrict__ bv,
    const unsigned short* __restrict__ whf, const unsigned short* __restrict__ wlf,
    unsigned short* __restrict__ qh, unsigned short* __restrict__ ql,
    unsigned short* __restrict__ kh, unsigned short* __restrict__ kl,
    unsigned short* __restrict__ vbf)
{
    __shared__ unsigned xpk[64 * 260 + 4];   // [pixel][c] packed (hi<<16|lo), ~65 KB

    const int tid  = threadIdx.x;
    const int w    = tid >> 6;
    const int lane = tid & 63;
    const int quad = lane >> 4;
    const int l16  = lane & 15;
    const int n0   = blockIdx.x * 64;
    const int b    = blockIdx.y;

    // ---- stage x tile: 64 coalesced row-chunks, convert to bf16 hi/lo ----
    {
        const int p  = tid & 63;
        const int cb = tid >> 6;
        const float* xbase = x + (size_t)b * C_ * N_ + n0 + p;
#pragma unroll 4
        for (int s = 0; s < 64; ++s) {
            const int c = s * 4 + cb;
            const float v = xbase[(size_t)c * N_];
            const unsigned short hb = f2bf(v);
            const unsigned short lb = f2bf(v - bf2f(hb));
            xpk[p * 260 + c] = (((unsigned)hb) << 16) | lb;
        }
    }
    __syncthreads();

    const frag* wh = (const frag*)whf;
    const frag* wl = (const frag*)wlf;
    const int n = n0 + w * 16 + l16;

    f32x4 acc[20];
#pragma unroll
    for (int g = 0; g < 20; ++g) acc[g] = (f32x4){0.f, 0.f, 0.f, 0.f};

    for (int kc = 0; kc < 8; ++kc) {
        const unsigned* row = &xpk[(w * 16 + l16) * 260 + kc * 32 + quad * 8];
        const uint4 A  = *(const uint4*)row;        // c0..c3 packed
        const uint4 Bv = *(const uint4*)(row + 4);  // c4..c7 packed
        frag bh, bl;
        unsigned* bhp = (unsigned*)&bh;
        unsigned* blp = (unsigned*)&bl;
        bhp[0] = __builtin_amdgcn_perm(A.y,  A.x,  0x07060302u);
        bhp[1] = __builtin_amdgcn_perm(A.w,  A.z,  0x07060302u);
        bhp[2] = __builtin_amdgcn_perm(Bv.y, Bv.x, 0x07060302u);
        bhp[3] = __builtin_amdgcn_perm(Bv.w, Bv.z, 0x07060302u);
        blp[0] = __builtin_amdgcn_perm(A.y,  A.x,  0x05040100u);
        blp[1] = __builtin_amdgcn_perm(A.w,  A.z,  0x05040100u);
        blp[2] = __builtin_amdgcn_perm(Bv.y, Bv.x, 0x05040100u);
        blp[3] = __builtin_amdgcn_perm(Bv.w, Bv.z, 0x05040100u);

#pragma unroll
        for (int g = 0; g < 4; ++g) {
            const frag ah = wh[(g * 8 + kc) * 64 + lane];
            const frag al = wl[(g * 8 + kc) * 64 + lane];
            acc[g] = __builtin_amdgcn_mfma_f32_16x16x32_bf16(ah, bh, acc[g], 0, 0, 0);
            acc[g] = __builtin_amdgcn_mfma_f32_16x16x32_bf16(al, bh, acc[g], 0, 0, 0);
            acc[g] = __builtin_amdgcn_mfma_f32_16x16x32_bf16(ah, bl, acc[g], 0, 0, 0);
        }
#pragma unroll
        for (int g = 4; g < 20; ++g) {
            const frag ah = wh[(g * 8 + kc) * 64 + lane];
            acc[g] = __builtin_amdgcn_mfma_f32_16x16x32_bf16(ah, bh, acc[g], 0, 0, 0);
        }
    }

    // ---- epilogue: bias add, store.  D row = quad*4+r, col = l16 = pixel ----
#pragma unroll
    for (int g = 0; g < 4; ++g) {
        const bool isq = (g < 2);
        const float* bias = isq ? bq : bk;
        const int dbase = (isq ? g : g - 2) * 16 + quad * 4;
        unsigned short hs[4], ls[4];
#pragma unroll
        for (int r = 0; r < 4; ++r) {
            const float f = acc[g][r] + bias[dbase + r];
            hs[r] = f2bf(f);
            ls[r] = f2bf(f - bf2f(hs[r]));
        }
        const size_t off = ((size_t)(b * N_ + n)) * 32 + dbase;
        *(uint2*)&(isq ? qh : kh)[off] = make_uint2(PK2(hs[0], hs[1]), PK2(hs[2], hs[3]));
        *(uint2*)&(isq ? ql : kl)[off] = make_uint2(PK2(ls[0], ls[1]), PK2(ls[2], ls[3]));
    }
#pragma unroll
    for (int g = 4; g < 20; ++g) {
#pragma unroll
        for (int r = 0; r < 4; ++r) {
            const int c = (g - 4) * 16 + quad * 4 + r;
            vbf[((size_t)b * C_ + c) * N_ + n] = f2bf(acc[g][r] + bv[c]);
        }
    }
}

// ---------------------------------------------------------------------------
// Kernel 2: MFMA flash attention — software-pipelined.
// Per iter: S from K regs (preloaded LAST iter) -> softmax -> pack -> barrier
//   -> issue V(jc) then K(jc+1) -> rescale -> PV.
// K loads fly across PV + loopback; V loads expose one short wait.
// p_s double-buffered -> single barrier per iteration.
// grid (N/64, B), 256 threads (4 waves).
// ---------------------------------------------------------------------------
__global__ __launch_bounds__(256, 2) void attn_kernel(
    const unsigned short* __restrict__ qh, const unsigned short* __restrict__ ql,
    const unsigned short* __restrict__ khg, const unsigned short* __restrict__ klg,
    const unsigned short* __restrict__ vbf,
    const float* __restrict__ x, const float* __restrict__ alpha_p,
    float* __restrict__ out)
{
    __shared__ __align__(16) short p_s[2][64 * PLD];   // ~34.8 KB
    __shared__ float alpha_s[2][64];
    __shared__ float l_s[64];

    const int tid  = threadIdx.x;
    const int w    = tid >> 6;
    const int lane = tid & 63;
    const int quad = lane >> 4;
    const int l16  = lane & 15;
    const int b    = blockIdx.y;
    const int i0   = blockIdx.x * 64;

    // Q B-frags (constant): lane holds q[i = i0+16w+l16][d = 8*quad..+8]
    const size_t qoff = ((size_t)(b * N_ + i0 + w * 16 + l16)) * 32 + quad * 8;
    const frag qhf = *(const frag*)(qh + qoff);
    const frag qlf = *(const frag*)(ql + qoff);

    const unsigned short* khb = khg + (size_t)b * N_ * 32;
    const unsigned short* klb = klg + (size_t)b * N_ * 32;
    const unsigned short* vb  = vbf + (size_t)b * C_ * N_;

    f32x4 o[4][4];   // [i-subtile][c-subtile], c = 64w + 16*ct + l16
#pragma unroll
    for (int it = 0; it < 4; ++it)
#pragma unroll
        for (int ct = 0; ct < 4; ++ct) o[it][ct] = (f32x4){0.f, 0.f, 0.f, 0.f};

    float m_run = -INFINITY, l_run = 0.f;

    // ---- preload K(0) into registers ----
    frag ka[8], kb[8];
#pragma unroll
    for (int js = 0; js < 8; ++js) {
        const size_t koff = ((size_t)(js * 16 + l16)) * 32 + quad * 8;
        ka[js] = *(const frag*)(khb + koff);
        kb[js] = *(const frag*)(klb + koff);
    }

    for (int jc = 0; jc < NJC; ++jc) {
        const int buf = jc & 1;

        // ---- S^T from preloaded K regs (3-MFMA split-bf16) ----
        f32x4 st[8];
#pragma unroll
        for (int js = 0; js < 8; ++js) {
            f32x4 s = (f32x4){0.f, 0.f, 0.f, 0.f};
            s = __builtin_amdgcn_mfma_f32_16x16x32_bf16(ka[js], qhf, s, 0, 0, 0);
            s = __builtin_amdgcn_mfma_f32_16x16x32_bf16(ka[js], qlf, s, 0, 0, 0);
            s = __builtin_amdgcn_mfma_f32_16x16x32_bf16(kb[js], qhf, s, 0, 0, 0);
            st[js] = s;
        }

        // ---- online softmax, rows i = w*16 + l16 (tree reductions) ----
        f32x4 t0 = fmax4(fmax4(st[0], st[1]), fmax4(st[2], st[3]));
        f32x4 t1 = fmax4(fmax4(st[4], st[5]), fmax4(st[6], st[7]));
        t0 = fmax4(t0, t1);
        float mx = fmaxf(fmaxf(t0[0], t0[1]), fmaxf(t0[2], t0[3]));
        mx = fmaxf(mx, __shfl_xor(mx, 16));
        mx = fmaxf(mx, __shfl_xor(mx, 32));
        const float mnew = fmaxf(m_run, mx);
        const float sc   = __expf(m_run - mnew);

        f32x4 ps4 = (f32x4){0.f, 0.f, 0.f, 0.f};
#pragma unroll
        for (int js = 0; js < 8; ++js) {
#pragma unroll
            for (int r = 0; r < 4; ++r) st[js][r] = __expf(st[js][r] - mnew);
            ps4[0] += st[js][0]; ps4[1] += st[js][1];
            ps4[2] += st[js][2]; ps4[3] += st[js][3];
        }
        float ps = (ps4[0] + ps4[1]) + (ps4[2] + ps4[3]);
        ps += __shfl_xor(ps, 16);
        ps += __shfl_xor(ps, 32);
        l_run = l_run * sc + ps;
        m_run = mnew;
        if (quad == 0) alpha_s[buf][w * 16 + l16] = sc;

        // ---- P -> bf16 (round-half-up + v_perm pack) -> LDS ----
#pragma unroll
        for (int js = 0; js < 8; ++js) {
            const unsigned a0 = __float_as_uint(st[js][0]) + 0x8000u;
            const unsigned a1 = __float_as_uint(st[js][1]) + 0x8000u;
            const unsigned a2 = __float_as_uint(st[js][2]) + 0x8000u;
            const unsigned a3 = __float_as_uint(st[js][3]) + 0x8000u;
            const unsigned p01 = __builtin_amdgcn_perm(a1, a0, 0x07060302u);
            const unsigned p23 = __builtin_amdgcn_perm(a3, a2, 0x07060302u);
            *(uint2*)&p_s[buf][(w * 16 + l16) * PLD + js * 16 + quad * 4] =
                make_uint2(p01, p23);
        }
        __syncthreads();   // single barrier; drains all in-flight loads too

        // ---- issue V(jc) FIRST (so PV's vmcnt wait leaves K outstanding) ----
        frag vf[4][4];
#pragma unroll
        for (int ks = 0; ks < 4; ++ks)
#pragma unroll
            for (int ct = 0; ct < 4; ++ct)
                vf[ks][ct] = *(const frag*)(vb
                    + (size_t)(w * 64 + ct * 16 + l16) * N_
                    + jc * 128 + ks * 32 + quad * 8);

        // ---- then issue K(jc+1); flies across PV + loopback ----
        {
            const int jn = (jc + 1 < NJC) ? jc + 1 : jc;
#pragma unroll
            for (int js = 0; js < 8; ++js) {
                const size_t koff = ((size_t)(jn * 128 + js * 16 + l16)) * 32 + quad * 8;
                ka[js] = *(const frag*)(khb + koff);
                kb[js] = *(const frag*)(klb + koff);
            }
        }

        // ---- rescale O ----
#pragma unroll
        for (int it = 0; it < 4; ++it)
#pragma unroll
            for (int r = 0; r < 4; ++r) {
                const float al = alpha_s[buf][it * 16 + quad * 4 + r];
#pragma unroll
                for (int ct = 0; ct < 4; ++ct) o[it][ct][r] *= al;
            }

        // ---- PV: A = P (LDS), B = V regs ----
#pragma unroll
        for (int ks = 0; ks < 4; ++ks) {
#pragma unroll
            for (int it = 0; it < 4; ++it) {
                const frag pf = *(const frag*)&p_s[buf][(it * 16 + l16) * PLD
                                                       + ks * 32 + quad * 8];
#pragma unroll
                for (int ct = 0; ct < 4; ++ct)
                    o[it][ct] = __builtin_amdgcn_mfma_f32_16x16x32_bf16(
                        pf, vf[ks][ct], o[it][ct], 0, 0, 0);
            }
        }
    }

    // ---- epilogue: out = alpha * O / l + x ----
    if (quad == 0) l_s[w * 16 + l16] = l_run;
    __syncthreads();
    const float av = alpha_p[0];

#pragma unroll
    for (int it = 0; it < 4; ++it) {
        float invl[4];
#pragma unroll
        for (int r = 0; r < 4; ++r) invl[r] = 1.f / l_s[it * 16 + quad * 4 + r];
#pragma unroll
        for (int ct = 0; ct < 4; ++ct) {
            const int c = w * 64 + ct * 16 + l16;
            const size_t base = (size_t)b * C_ * N_ + (size_t)c * N_
                                + i0 + it * 16 + quad * 4;
            const float4 xv = *(const float4*)(x + base);
            float4 ov;
            ov.x = av * (o[it][ct][0] * invl[0]) + xv.x;
            ov.y = av * (o[it][ct][1] * invl[1]) + xv.y;
            ov.z = av * (o[it][ct][2] * invl[2]) + xv.z;
            ov.w = av * (o[it][ct][3] * invl[3]) + xv.w;
            *(float4*)(out + base) = ov;
        }
    }
}

// ---------------------------------------------------------------------------
extern "C" void kernel_launch(void* const* d_in, const int* in_sizes, int n_in,
                              void* d_out, int out_size, void* d_ws, size_t ws_size,
                              hipStream_t stream)
{
    const float* x  = (const float*)d_in[0];
    const float* wq = (const float*)d_in[1];
    const float* bq = (const float*)d_in[2];
    const float* wk = (const float*)d_in[3];
    const float* bk = (const float*)d_in[4];
    const float* wv = (const float*)d_in[5];
    const float* bv = (const float*)d_in[6];
    const float* al = (const float*)d_in[7];
    float* out = (float*)d_out;

    // workspace: qh,ql,kh,kl 2MB each; vbf 16MB; whf 160KB; wlf 32KB
    char* ws = (char*)d_ws;
    unsigned short* qh  = (unsigned short*)(ws + 0);
    unsigned short* ql  = (unsigned short*)(ws + (size_t)2  * 1024 * 1024);
    unsigned short* kh  = (unsigned short*)(ws + (size_t)4  * 1024 * 1024);
    unsigned short* kl  = (unsigned short*)(ws + (size_t)6  * 1024 * 1024);
    unsigned short* vbf = (unsigned short*)(ws + (size_t)8  * 1024 * 1024);
    unsigned short* whf = (unsigned short*)(ws + (size_t)24 * 1024 * 1024);
    unsigned short* wlf = (unsigned short*)(ws + (size_t)24 * 1024 * 1024 + 256 * 1024);

    wprep_kernel<<<40, 256, 0, stream>>>(wq, wk, wv, whf, wlf);
    proj_kernel<<<dim3(N_ / 64, B_), 256, 0, stream>>>(
        x, bq, bk, bv, whf, wlf, qh, ql, kh, kl, vbf);
    attn_kernel<<<dim3(N_ / 64, B_), 256, 0, stream>>>(
        qh, ql, kh, kl, vbf, x, al, out);
}

// Round 6
// 232.434 us; speedup vs baseline: 1.3768x; 1.2719x over previous
//
#include <hip/hip_runtime.h>
#include <math.h>

// Problem constants (fixed by the reference)
#define B_  8
#define C_  256
#define N_  4096        // H*W
#define NJC (N_ / 128)  // 32 j-iterations of 128
#define PLD 136         // p_s row stride in shorts (128 + 8 pad)

using frag  = __attribute__((ext_vector_type(8))) short;   // 8 bf16 = 16 B
using f32x4 = __attribute__((ext_vector_type(4))) float;

__device__ __forceinline__ unsigned short f2bf(float f) {   // RNE fp32 -> bf16
    unsigned u = __float_as_uint(f);
    u += 0x7fffu + ((u >> 16) & 1u);
    return (unsigned short)(u >> 16);
}
__device__ __forceinline__ float bf2f(unsigned short h) {
    return __uint_as_float(((unsigned)h) << 16);
}
#define PK2(a, b) (((unsigned)(a)) | (((unsigned)(b)) << 16))

__device__ __forceinline__ f32x4 fmax4(f32x4 a, f32x4 b) {
    f32x4 r;
    r[0] = fmaxf(a[0], b[0]); r[1] = fmaxf(a[1], b[1]);
    r[2] = fmaxf(a[2], b[2]); r[3] = fmaxf(a[3], b[3]);
    return r;
}

// ---------------------------------------------------------------------------
// Kernel 0: weight prep -> frag-ordered bf16 weights in ws.
//   whf: 20 groups x 8 kc x 64 lanes x 8 bf16  (g 0,1=q; 2,3=k; 4..19=v)
//   wlf: 4 groups (q,k lo part), same shape.
// ---------------------------------------------------------------------------
__global__ __launch_bounds__(256) void wprep_kernel(
    const float* __restrict__ wq, const float* __restrict__ wk,
    const float* __restrict__ wv,
    unsigned short* __restrict__ whf, unsigned short* __restrict__ wlf)
{
    const int fid  = blockIdx.x * 256 + threadIdx.x;   // 0..10239
    if (fid >= 20 * 8 * 64) return;
    const int g    = fid >> 9;
    const int kc   = (fid >> 6) & 7;
    const int lane = fid & 63;
    const int r16  = lane & 15, q = lane >> 4;

    const float* src; int row;
    if (g < 2)      { src = wq; row = g * 16 + r16; }
    else if (g < 4) { src = wk; row = (g - 2) * 16 + r16; }
    else            { src = wv; row = (g - 4) * 16 + r16; }

    const float* wp = src + row * 256 + kc * 32 + q * 8;
    float v[8];
#pragma unroll
    for (int j = 0; j < 8; ++j) v[j] = wp[j];

    unsigned short h[8];
#pragma unroll
    for (int j = 0; j < 8; ++j) h[j] = f2bf(v[j]);
    uint4 U;
    U.x = PK2(h[0], h[1]); U.y = PK2(h[2], h[3]);
    U.z = PK2(h[4], h[5]); U.w = PK2(h[6], h[7]);
    *(uint4*)&whf[(size_t)fid * 8] = U;

    if (g < 4) {
        unsigned short l[8];
#pragma unroll
        for (int j = 0; j < 8; ++j) l[j] = f2bf(v[j] - bf2f(h[j]));
        uint4 V;
        V.x = PK2(l[0], l[1]); V.y = PK2(l[2], l[3]);
        V.z = PK2(l[4], l[5]); V.w = PK2(l[6], l[7]);
        *(uint4*)&wlf[(size_t)fid * 8] = V;
    }
}

// ---------------------------------------------------------------------------
// Kernel 1: MFMA qkv projection — x staged ONCE into LDS (packed hi|lo).
// grid (N/64, B), 256 threads (4 waves).
// ---------------------------------------------------------------------------
__global__ __launch_bounds__(256, 2) void proj_kernel(
    const float* __restrict__ x,
    const float* __restrict__ bq, const float* __restrict__ bk,
    const float* __restrict__ bv,
    const unsigned short* __restrict__ whf, const unsigned short* __restrict__ wlf,
    unsigned short* __restrict__ qh, unsigned short* __restrict__ ql,
    unsigned short* __restrict__ kh, unsigned short* __restrict__ kl,
    unsigned short* __restrict__ vbf)
{
    __shared__ unsigned xpk[64 * 260 + 4];   // [pixel][c] packed (hi<<16|lo)

    const int tid  = threadIdx.x;
    const int w    = tid >> 6;
    const int lane = tid & 63;
    const int quad = lane >> 4;
    const int l16  = lane & 15;
    const int n0   = blockIdx.x * 64;
    const int b    = blockIdx.y;

    // ---- stage x tile: 64 coalesced row-chunks, convert to bf16 hi/lo ----
    {
        const int p  = tid & 63;
        const int cb = tid >> 6;
        const float* xbase = x + (size_t)b * C_ * N_ + n0 + p;
#pragma unroll 16
        for (int s = 0; s < 64; ++s) {
            const int c = s * 4 + cb;
            const float v = xbase[(size_t)c * N_];
            const unsigned short hb = f2bf(v);
            const unsigned short lb = f2bf(v - bf2f(hb));
            xpk[p * 260 + c] = (((unsigned)hb) << 16) | lb;
        }
    }
    __syncthreads();

    const frag* wh = (const frag*)whf;
    const frag* wl = (const frag*)wlf;
    const int n = n0 + w * 16 + l16;

    f32x4 acc[20];
#pragma unroll
    for (int g = 0; g < 20; ++g) acc[g] = (f32x4){0.f, 0.f, 0.f, 0.f};

    for (int kc = 0; kc < 8; ++kc) {
        const unsigned* row = &xpk[(w * 16 + l16) * 260 + kc * 32 + quad * 8];
        const uint4 A  = *(const uint4*)row;
        const uint4 Bv = *(const uint4*)(row + 4);
        frag bh, bl;
        unsigned* bhp = (unsigned*)&bh;
        unsigned* blp = (unsigned*)&bl;
        bhp[0] = __builtin_amdgcn_perm(A.y,  A.x,  0x07060302u);
        bhp[1] = __builtin_amdgcn_perm(A.w,  A.z,  0x07060302u);
        bhp[2] = __builtin_amdgcn_perm(Bv.y, Bv.x, 0x07060302u);
        bhp[3] = __builtin_amdgcn_perm(Bv.w, Bv.z, 0x07060302u);
        blp[0] = __builtin_amdgcn_perm(A.y,  A.x,  0x05040100u);
        blp[1] = __builtin_amdgcn_perm(A.w,  A.z,  0x05040100u);
        blp[2] = __builtin_amdgcn_perm(Bv.y, Bv.x, 0x05040100u);
        blp[3] = __builtin_amdgcn_perm(Bv.w, Bv.z, 0x05040100u);

#pragma unroll
        for (int g = 0; g < 4; ++g) {
            const frag ah = wh[(g * 8 + kc) * 64 + lane];
            const frag al = wl[(g * 8 + kc) * 64 + lane];
            acc[g] = __builtin_amdgcn_mfma_f32_16x16x32_bf16(ah, bh, acc[g], 0, 0, 0);
            acc[g] = __builtin_amdgcn_mfma_f32_16x16x32_bf16(al, bh, acc[g], 0, 0, 0);
            acc[g] = __builtin_amdgcn_mfma_f32_16x16x32_bf16(ah, bl, acc[g], 0, 0, 0);
        }
#pragma unroll
        for (int g = 4; g < 20; ++g) {
            const frag ah = wh[(g * 8 + kc) * 64 + lane];
            acc[g] = __builtin_amdgcn_mfma_f32_16x16x32_bf16(ah, bh, acc[g], 0, 0, 0);
        }
    }

    // ---- epilogue: bias add, store ----
#pragma unroll
    for (int g = 0; g < 4; ++g) {
        const bool isq = (g < 2);
        const float* bias = isq ? bq : bk;
        const int dbase = (isq ? g : g - 2) * 16 + quad * 4;
        unsigned short hs[4], ls[4];
#pragma unroll
        for (int r = 0; r < 4; ++r) {
            const float f = acc[g][r] + bias[dbase + r];
            hs[r] = f2bf(f);
            ls[r] = f2bf(f - bf2f(hs[r]));
        }
        const size_t off = ((size_t)(b * N_ + n)) * 32 + dbase;
        *(uint2*)&(isq ? qh : kh)[off] = make_uint2(PK2(hs[0], hs[1]), PK2(hs[2], hs[3]));
        *(uint2*)&(isq ? ql : kl)[off] = make_uint2(PK2(ls[0], ls[1]), PK2(ls[2], ls[3]));
    }
#pragma unroll
    for (int g = 4; g < 20; ++g) {
#pragma unroll
        for (int r = 0; r < 4; ++r) {
            const int c = (g - 4) * 16 + quad * 4 + r;
            vbf[((size_t)b * C_ + c) * N_ + n] = f2bf(acc[g][r] + bv[c]);
        }
    }
}

// ---------------------------------------------------------------------------
// Kernel 2: MFMA flash attention v2.
// Block = 512 threads (8 waves), i-tile = 128 rows. grid (N/128, B) = 256
// blocks = 1/CU. Wave w: S+softmax for i-subtile w; PV for channels
// w*32..w*32+32 x all 128 rows.
// K double-buffered in LDS (staged via regs during softmax; single barrier
// per iter, vmcnt naturally 0 at the barrier). p_s double-buffered.
// ---------------------------------------------------------------------------
__global__ __launch_bounds__(512, 2) void attn_kernel(
    const unsigned short* __restrict__ qh, const unsigned short* __restrict__ ql,
    const unsigned short* __restrict__ khg, const unsigned short* __restrict__ klg,
    const unsigned short* __restrict__ vbf,
    const float* __restrict__ x, const float* __restrict__ alpha_p,
    float* __restrict__ out)
{
    __shared__ __align__(16) short kbuf[2][2][128 * 32];   // 32 KB
    __shared__ __align__(16) short p_s[2][128 * PLD];      // ~69.6 KB
    __shared__ float alpha_s[2][128];
    __shared__ float l_s[128];

    const int tid  = threadIdx.x;
    const int w    = tid >> 6;        // wave 0..7
    const int lane = tid & 63;
    const int quad = lane >> 4;
    const int l16  = lane & 15;
    const int b    = blockIdx.y;
    const int i0   = blockIdx.x * 128;

    // Q B-frags (constant): lane holds q[i = i0+16w+l16][d = 8*quad..+8]
    const size_t qoff = ((size_t)(b * N_ + i0 + w * 16 + l16)) * 32 + quad * 8;
    const frag qhf = *(const frag*)(qh + qoff);
    const frag qlf = *(const frag*)(ql + qoff);

    const unsigned short* khb = khg + (size_t)b * N_ * 32;
    const unsigned short* klb = klg + (size_t)b * N_ * 32;
    const unsigned short* vb  = vbf + (size_t)b * C_ * N_;

    f32x4 o[8][2];   // [i-subtile][c-subtile], c = w*32 + ct*16 + l16
#pragma unroll
    for (int it = 0; it < 8; ++it) {
        o[it][0] = (f32x4){0.f, 0.f, 0.f, 0.f};
        o[it][1] = (f32x4){0.f, 0.f, 0.f, 0.f};
    }

    float m_run = -INFINITY, l_run = 0.f;

    const int stoff = w * 512 + lane * 8;   // staging offset (shorts, 16B/lane)

    // ---- prologue: stage K(0) into kbuf[0] ----
    {
        const uint4 h0 = *(const uint4*)(khb + stoff);
        const uint4 l0 = *(const uint4*)(klb + stoff);
        *(uint4*)&kbuf[0][0][stoff] = h0;
        *(uint4*)&kbuf[0][1][stoff] = l0;
    }
    __syncthreads();

    for (int jc = 0; jc < NJC; ++jc) {
        const int bf = jc & 1;

        // ---- S^T from kbuf[bf] (3-MFMA split-bf16), D[m=j][n=i] ----
        f32x4 st[8];
#pragma unroll
        for (int js = 0; js < 8; ++js) {
            const frag ka = *(const frag*)&kbuf[bf][0][(js * 16 + l16) * 32 + quad * 8];
            const frag kb2 = *(const frag*)&kbuf[bf][1][(js * 16 + l16) * 32 + quad * 8];
            f32x4 s = (f32x4){0.f, 0.f, 0.f, 0.f};
            s = __builtin_amdgcn_mfma_f32_16x16x32_bf16(ka, qhf, s, 0, 0, 0);
            s = __builtin_amdgcn_mfma_f32_16x16x32_bf16(ka, qlf, s, 0, 0, 0);
            s = __builtin_amdgcn_mfma_f32_16x16x32_bf16(kb2, qhf, s, 0, 0, 0);
            st[js] = s;
        }

        // ---- issue K(jc+1) global->regs (latency hidden by softmax) ----
        const int jn = (jc + 1 < NJC) ? jc + 1 : jc;
        const uint4 knh = *(const uint4*)(khb + (size_t)jn * 4096 + stoff);
        const uint4 knl = *(const uint4*)(klb + (size_t)jn * 4096 + stoff);

        // ---- online softmax, rows i = w*16 + l16 ----
        f32x4 t0 = fmax4(fmax4(st[0], st[1]), fmax4(st[2], st[3]));
        f32x4 t1 = fmax4(fmax4(st[4], st[5]), fmax4(st[6], st[7]));
        t0 = fmax4(t0, t1);
        float mx = fmaxf(fmaxf(t0[0], t0[1]), fmaxf(t0[2], t0[3]));
        mx = fmaxf(mx, __shfl_xor(mx, 16));
        mx = fmaxf(mx, __shfl_xor(mx, 32));
        const float mnew = fmaxf(m_run, mx);
        const float sc   = __expf(m_run - mnew);

        f32x4 ps4 = (f32x4){0.f, 0.f, 0.f, 0.f};
#pragma unroll
        for (int js = 0; js < 8; ++js) {
#pragma unroll
            for (int r = 0; r < 4; ++r) st[js][r] = __expf(st[js][r] - mnew);
            ps4[0] += st[js][0]; ps4[1] += st[js][1];
            ps4[2] += st[js][2]; ps4[3] += st[js][3];
        }
        float ps = (ps4[0] + ps4[1]) + (ps4[2] + ps4[3]);
        ps += __shfl_xor(ps, 16);
        ps += __shfl_xor(ps, 32);
        l_run = l_run * sc + ps;
        m_run = mnew;
        if (quad == 0) alpha_s[bf][w * 16 + l16] = sc;

        // ---- P -> bf16 (round-half-up + v_perm pack) -> p_s[bf] ----
#pragma unroll
        for (int js = 0; js < 8; ++js) {
            const unsigned a0 = __float_as_uint(st[js][0]) + 0x8000u;
            const unsigned a1 = __float_as_uint(st[js][1]) + 0x8000u;
            const unsigned a2 = __float_as_uint(st[js][2]) + 0x8000u;
            const unsigned a3 = __float_as_uint(st[js][3]) + 0x8000u;
            const unsigned p01 = __builtin_amdgcn_perm(a1, a0, 0x07060302u);
            const unsigned p23 = __builtin_amdgcn_perm(a3, a2, 0x07060302u);
            *(uint2*)&p_s[bf][(w * 16 + l16) * PLD + js * 16 + quad * 4] =
                make_uint2(p01, p23);
        }

        // ---- stage K(jc+1) into kbuf[bf^1] (regs arrived during softmax) ----
        *(uint4*)&kbuf[bf ^ 1][0][stoff] = knh;
        *(uint4*)&kbuf[bf ^ 1][1][stoff] = knl;

        __syncthreads();   // single barrier; vmcnt already 0 -> free drain

        // ---- V loads for this chunk: c = w*32 + ct*16 + l16 ----
        frag vf[4][2];
#pragma unroll
        for (int ks = 0; ks < 4; ++ks)
#pragma unroll
            for (int ct = 0; ct < 2; ++ct)
                vf[ks][ct] = *(const frag*)(vb
                    + (size_t)(w * 32 + ct * 16 + l16) * N_
                    + jc * 128 + ks * 32 + quad * 8);

        // ---- rescale O ----
#pragma unroll
        for (int it = 0; it < 8; ++it)
#pragma unroll
            for (int r = 0; r < 4; ++r) {
                const float al = alpha_s[bf][it * 16 + quad * 4 + r];
                o[it][0][r] *= al;
                o[it][1][r] *= al;
            }

        // ---- PV: A = P (LDS), B = V regs.  D[m=i][n=c] ----
#pragma unroll
        for (int ks = 0; ks < 4; ++ks) {
#pragma unroll
            for (int it = 0; it < 8; ++it) {
                const frag pf = *(const frag*)&p_s[bf][(it * 16 + l16) * PLD
                                                       + ks * 32 + quad * 8];
                o[it][0] = __builtin_amdgcn_mfma_f32_16x16x32_bf16(pf, vf[ks][0], o[it][0], 0, 0, 0);
                o[it][1] = __builtin_amdgcn_mfma_f32_16x16x32_bf16(pf, vf[ks][1], o[it][1], 0, 0, 0);
            }
        }
    }

    // ---- epilogue: out = alpha * O / l + x ----
    if (quad == 0) l_s[w * 16 + l16] = l_run;
    __syncthreads();
    const float av = alpha_p[0];

#pragma unroll
    for (int it = 0; it < 8; ++it) {
        float invl[4];
#pragma unroll
        for (int r = 0; r < 4; ++r) invl[r] = 1.f / l_s[it * 16 + quad * 4 + r];
#pragma unroll
        for (int ct = 0; ct < 2; ++ct) {
            const int c = w * 32 + ct * 16 + l16;
            const size_t base = (size_t)b * C_ * N_ + (size_t)c * N_
                                + i0 + it * 16 + quad * 4;
            const float4 xv = *(const float4*)(x + base);
            float4 ov;
            ov.x = av * (o[it][ct][0] * invl[0]) + xv.x;
            ov.y = av * (o[it][ct][1] * invl[1]) + xv.y;
            ov.z = av * (o[it][ct][2] * invl[2]) + xv.z;
            ov.w = av * (o[it][ct][3] * invl[3]) + xv.w;
            *(float4*)(out + base) = ov;
        }
    }
}

// ---------------------------------------------------------------------------
extern "C" void kernel_launch(void* const* d_in, const int* in_sizes, int n_in,
                              void* d_out, int out_size, void* d_ws, size_t ws_size,
                              hipStream_t stream)
{
    const float* x  = (const float*)d_in[0];
    const float* wq = (const float*)d_in[1];
    const float* bq = (const float*)d_in[2];
    const float* wk = (const float*)d_in[3];
    const float* bk = (const float*)d_in[4];
    const float* wv = (const float*)d_in[5];
    const float* bv = (const float*)d_in[6];
    const float* al = (const float*)d_in[7];
    float* out = (float*)d_out;

    // workspace: qh,ql,kh,kl 2MB each; vbf 16MB; whf 160KB; wlf 32KB
    char* ws = (char*)d_ws;
    unsigned short* qh  = (unsigned short*)(ws + 0);
    unsigned short* ql  = (unsigned short*)(ws + (size_t)2  * 1024 * 1024);
    unsigned short* kh  = (unsigned short*)(ws + (size_t)4  * 1024 * 1024);
    unsigned short* kl  = (unsigned short*)(ws + (size_t)6  * 1024 * 1024);
    unsigned short* vbf = (unsigned short*)(ws + (size_t)8  * 1024 * 1024);
    unsigned short* whf = (unsigned short*)(ws + (size_t)24 * 1024 * 1024);
    unsigned short* wlf = (unsigned short*)(ws + (size_t)24 * 1024 * 1024 + 256 * 1024);

    wprep_kernel<<<40, 256, 0, stream>>>(wq, wk, wv, whf, wlf);
    proj_kernel<<<dim3(N_ / 64, B_), 256, 0, stream>>>(
        x, bq, bk, bv, whf, wlf, qh, ql, kh, kl, vbf);
    attn_kernel<<<dim3(N_ / 128, B_), 512, 0, stream>>>(
        qh, ql, kh, kl, vbf, x, al, out);
}